// Round 3
// baseline (975.091 us; speedup 1.0000x reference)
//
#include <hip/hip_runtime.h>
#include <hip/hip_bf16.h>

__device__ __forceinline__ float leaky(float v) { return v >= 0.f ? v : 0.2f * v; }

// ---------------- CSR build ----------------
__global__ void hist_kernel(const int* __restrict__ dst, int E, int* __restrict__ cnt) {
    int e = blockIdx.x * blockDim.x + threadIdx.x;
    if (e < E) atomicAdd(&cnt[dst[e]], 1);
}

__global__ __launch_bounds__(1024) void scan_kernel(const int* __restrict__ cnt,
                                                    int* __restrict__ row_ptr,
                                                    int* __restrict__ cursor, int N) {
    __shared__ int part[1024];
    int tid = threadIdx.x;
    int per = (N + 1023) >> 10;
    int s0 = tid * per, s1 = min(s0 + per, N);
    int s = 0;
    for (int i = s0; i < s1; i++) s += cnt[i] + 1;  // +1 = self loop
    part[tid] = s;
    __syncthreads();
    for (int off = 1; off < 1024; off <<= 1) {
        int v = (tid >= off) ? part[tid - off] : 0;
        __syncthreads();
        part[tid] += v;
        __syncthreads();
    }
    int base = (tid == 0) ? 0 : part[tid - 1];
    for (int i = s0; i < s1; i++) {
        row_ptr[i] = base; cursor[i] = base;
        base += cnt[i] + 1;
    }
    if (tid == 0) row_ptr[N] = part[1023];
}

__global__ void scatter_kernel(const int* __restrict__ src, const int* __restrict__ dst,
                               int E, int N, int* __restrict__ cursor, int* __restrict__ csr_src) {
    int e = blockIdx.x * blockDim.x + threadIdx.x;
    if (e >= E + N) return;
    int s, d;
    if (e < E) { s = src[e]; d = dst[e]; }
    else       { s = e - E;  d = s; }
    int pos = atomicAdd(&cursor[d], 1);
    csr_src[pos] = s;
}

// ---------------- GEMM: C[M,Nn] = A[M,K] * B[K,Nn] (+bias)(+relu), fp32 ----------------
template <bool RELU, bool BIAS>
__global__ __launch_bounds__(256) void gemm_kernel(const float* __restrict__ A,
                                                   const float* __restrict__ B,
                                                   const float* __restrict__ bias,
                                                   float* __restrict__ C,
                                                   int M, int K, int Nn) {
    __shared__ float As[64][65];
    __shared__ float Bs[64][68];
    int tid = threadIdx.x;
    int tx = tid & 15, ty = tid >> 4;
    int row0 = blockIdx.x * 64, col0 = blockIdx.y * 64;
    float acc[4][4] = {};

    for (int kt = 0; kt < K; kt += 64) {
        {
            int r = tid >> 2;
            int kc = (tid & 3) * 16;
            int grow = row0 + r;
            if (grow < M) {
                size_t base = (size_t)grow * K + kt + kc;
#pragma unroll
                for (int i = 0; i < 16; i++) As[r][kc + i] = A[base + i];
            } else {
#pragma unroll
                for (int i = 0; i < 16; i++) As[r][kc + i] = 0.f;
            }
        }
        {
            int kr = tid >> 2;
            int nc = (tid & 3) * 16;
            size_t base = (size_t)(kt + kr) * Nn + col0 + nc;
#pragma unroll
            for (int i = 0; i < 16; i++) Bs[kr][nc + i] = B[base + i];
        }
        __syncthreads();
#pragma unroll
        for (int k = 0; k < 64; k++) {
            float b0v = Bs[k][tx * 4 + 0];
            float b1v = Bs[k][tx * 4 + 1];
            float b2v = Bs[k][tx * 4 + 2];
            float b3v = Bs[k][tx * 4 + 3];
#pragma unroll
            for (int i = 0; i < 4; i++) {
                float av = As[ty * 4 + i][k];
                acc[i][0] += av * b0v;
                acc[i][1] += av * b1v;
                acc[i][2] += av * b2v;
                acc[i][3] += av * b3v;
            }
        }
        __syncthreads();
    }

    float bv0 = 0.f, bv1 = 0.f, bv2 = 0.f, bv3 = 0.f;
    if (BIAS) {
        bv0 = bias[col0 + tx * 4 + 0];
        bv1 = bias[col0 + tx * 4 + 1];
        bv2 = bias[col0 + tx * 4 + 2];
        bv3 = bias[col0 + tx * 4 + 3];
    }
#pragma unroll
    for (int i = 0; i < 4; i++) {
        int r = row0 + ty * 4 + i;
        if (r < M) {
            float v0 = acc[i][0] + bv0;
            float v1 = acc[i][1] + bv1;
            float v2 = acc[i][2] + bv2;
            float v3 = acc[i][3] + bv3;
            if (RELU) {
                v0 = fmaxf(v0, 0.f); v1 = fmaxf(v1, 0.f);
                v2 = fmaxf(v2, 0.f); v3 = fmaxf(v3, 0.f);
            }
            size_t o = (size_t)r * Nn + col0 + tx * 4;
            C[o + 0] = v0; C[o + 1] = v1; C[o + 2] = v2; C[o + 3] = v3;
        }
    }
}

// ---------------- alpha_s/alpha_d per node ----------------
template <int H>
__global__ __launch_bounds__(256) void alphas_kernel(const float* __restrict__ h,
                                                     const float* __restrict__ a_src,
                                                     const float* __restrict__ a_dst,
                                                     float* __restrict__ alpha_s,
                                                     float* __restrict__ alpha_d, int N) {
    int lane = threadIdx.x & 63;
    int node = blockIdx.x * (blockDim.x >> 6) + (threadIdx.x >> 6);
    if (node >= N) return;
    if (H == 4) {
        int head = lane >> 4;
        int c4 = (lane & 15) * 4;
        const float* hp = h + (size_t)node * 256 + head * 64 + c4;
        float s = 0.f, d = 0.f;
#pragma unroll
        for (int j = 0; j < 4; j++) {
            float hv = hp[j];
            s += hv * a_src[head * 64 + c4 + j];
            d += hv * a_dst[head * 64 + c4 + j];
        }
#pragma unroll
        for (int off = 1; off < 16; off <<= 1) {
            s += __shfl_xor(s, off);
            d += __shfl_xor(d, off);
        }
        if ((lane & 15) == 0) {
            alpha_s[node * 4 + head] = s;
            alpha_d[node * 4 + head] = d;
        }
    } else {
        float hv = h[(size_t)node * 64 + lane];
        float s = hv * a_src[lane];
        float d = hv * a_dst[lane];
#pragma unroll
        for (int off = 1; off < 64; off <<= 1) {
            s += __shfl_xor(s, off);
            d += __shfl_xor(d, off);
        }
        if (lane == 0) { alpha_s[node] = s; alpha_d[node] = d; }
    }
}

// ---------------- per-dst softmax-weighted aggregation (one wave per node) ----------------
template <int H, bool RELU>
__global__ __launch_bounds__(256) void aggregate_kernel(const float* __restrict__ hsrc,
                                                        const float* __restrict__ alpha_s,
                                                        const float* __restrict__ alpha_d,
                                                        const int* __restrict__ row_ptr,
                                                        const int* __restrict__ csr_src,
                                                        const float* __restrict__ bias,
                                                        float* __restrict__ out, int N) {
    int lane = threadIdx.x & 63;
    int node = blockIdx.x * (blockDim.x >> 6) + (threadIdx.x >> 6);
    if (node >= N) return;
    int rs = row_ptr[node], re = row_ptr[node + 1];

    if (H == 4) {
        int head = lane >> 4;
        float ad = alpha_d[node * 4 + head];
        float m = -1e30f;
        for (int i = rs; i < re; i++) {
            int s = csr_src[i];
            s = min(max(s, 0), N - 1);
            float as = alpha_s[(size_t)s * 4 + head];
            m = fmaxf(m, leaky(as + ad));
        }
        int c4 = (lane & 15) * 4;
        float a0 = 0.f, a1 = 0.f, a2 = 0.f, a3 = 0.f, den = 0.f;
        for (int i = rs; i < re; i++) {
            int s = csr_src[i];
            s = min(max(s, 0), N - 1);
            float as = alpha_s[(size_t)s * 4 + head];
            float arg = leaky(as + ad) - m;
            float w = __expf(fminf(arg, 0.f));
            den += w;
            const float* hp = hsrc + (size_t)s * 256 + head * 64 + c4;
            a0 += w * hp[0]; a1 += w * hp[1]; a2 += w * hp[2]; a3 += w * hp[3];
        }
        float inv = 1.f / (den + 1e-16f);
        int cbase = head * 64 + c4;
        float v0 = a0 * inv + bias[cbase + 0];
        float v1 = a1 * inv + bias[cbase + 1];
        float v2 = a2 * inv + bias[cbase + 2];
        float v3 = a3 * inv + bias[cbase + 3];
        if (RELU) {
            v0 = fmaxf(v0, 0.f); v1 = fmaxf(v1, 0.f);
            v2 = fmaxf(v2, 0.f); v3 = fmaxf(v3, 0.f);
        }
        size_t o = (size_t)node * 256 + cbase;
        out[o + 0] = v0; out[o + 1] = v1; out[o + 2] = v2; out[o + 3] = v3;
    } else {
        float ad = alpha_d[node];
        float m = -1e30f;
        for (int i = rs; i < re; i++) {
            int s = csr_src[i];
            s = min(max(s, 0), N - 1);
            m = fmaxf(m, leaky(alpha_s[s] + ad));
        }
        float acc = 0.f, den = 0.f;
        for (int i = rs; i < re; i++) {
            int s = csr_src[i];
            s = min(max(s, 0), N - 1);
            float arg = leaky(alpha_s[s] + ad) - m;
            float w = __expf(fminf(arg, 0.f));
            den += w;
            acc += w * hsrc[(size_t)s * 64 + lane];
        }
        float v = acc / (den + 1e-16f) + bias[lane];
        if (RELU) v = fmaxf(v, 0.f);
        out[(size_t)node * 64 + lane] = v;
    }
}

// ---------------- head MLP: out = (relu(h@Wo1+bo1))@Wo2 + bo2 ----------------
__global__ __launch_bounds__(256) void mlp_head_kernel(const float* __restrict__ hin,
                                                       const float* __restrict__ Wo1,
                                                       const float* __restrict__ bo1,
                                                       const float* __restrict__ Wo2,
                                                       const float* __restrict__ bo2,
                                                       float* __restrict__ out, int N) {
    __shared__ float w1[64 * 32];
    __shared__ float w2[32];
    __shared__ float b1s[32];
    int tid = threadIdx.x;
#pragma unroll
    for (int i = 0; i < 8; i++) w1[tid + i * 256] = Wo1[tid + i * 256];
    if (tid < 32) { w2[tid] = Wo2[tid]; b1s[tid] = bo1[tid]; }
    __syncthreads();
    int n = blockIdx.x * blockDim.x + tid;
    if (n >= N) return;
    float hrow[64];
    const float* pr = hin + (size_t)n * 64;
#pragma unroll
    for (int i = 0; i < 64; i++) hrow[i] = pr[i];
    float sum = 0.f;
    for (int j = 0; j < 32; j++) {
        float a = b1s[j];
#pragma unroll
        for (int k = 0; k < 64; k++) a += hrow[k] * w1[k * 32 + j];
        a = fmaxf(a, 0.f);
        sum += a * w2[j];
    }
    out[n] = sum + bo2[0];
}

// ---------------- launch ----------------
extern "C" void kernel_launch(void* const* d_in, const int* in_sizes, int n_in,
                              void* d_out, int out_size, void* d_ws, size_t ws_size,
                              hipStream_t stream) {
    // Reference dtypes: all tensors float32, edge_index int32, output float32.
    const float* x     = (const float*)d_in[0];
    const float* W_emb = (const float*)d_in[1];
    const float* b_emb = (const float*)d_in[2];
    const float* W0    = (const float*)d_in[3];
    const float* as0   = (const float*)d_in[4];
    const float* ad0   = (const float*)d_in[5];
    const float* b0    = (const float*)d_in[6];
    const float* W1    = (const float*)d_in[7];
    const float* as1   = (const float*)d_in[8];
    const float* ad1   = (const float*)d_in[9];
    const float* b1    = (const float*)d_in[10];
    const float* W2    = (const float*)d_in[11];
    const float* as2   = (const float*)d_in[12];
    const float* ad2   = (const float*)d_in[13];
    const float* b2    = (const float*)d_in[14];
    const float* Wo1   = (const float*)d_in[15];
    const float* bo1   = (const float*)d_in[16];
    const float* Wo2   = (const float*)d_in[17];
    const float* bo2   = (const float*)d_in[18];
    const int* eidx    = (const int*)d_in[19];

    const int N = in_sizes[0] / 128;
    const int E = in_sizes[19] / 2;
    const int* esrc = eidx;
    const int* edst = eidx + E;

    char* w = (char*)d_ws;
    auto alloc = [&](size_t bytes) {
        char* p = w;
        w += (bytes + 255) & ~(size_t)255;
        return (void*)p;
    };
    float* bufA    = (float*)alloc((size_t)N * 256 * 4);
    float* bufB    = (float*)alloc((size_t)N * 256 * 4);
    float* aS      = (float*)alloc((size_t)N * 4 * 4);
    float* aD      = (float*)alloc((size_t)N * 4 * 4);
    int*   row_ptr = (int*)alloc((size_t)(N + 1) * 4);
    int*   cursor  = (int*)alloc((size_t)N * 4);
    int*   cnt     = (int*)alloc((size_t)N * 4);
    int*   csr     = (int*)alloc((size_t)(E + N) * 4);

    hipMemsetAsync(cnt, 0, (size_t)N * 4, stream);
    hist_kernel<<<(E + 255) / 256, 256, 0, stream>>>(edst, E, cnt);
    scan_kernel<<<1, 1024, 0, stream>>>(cnt, row_ptr, cursor, N);
    scatter_kernel<<<(E + N + 255) / 256, 256, 0, stream>>>(esrc, edst, E, N, cursor, csr);

    int gm = (N + 63) / 64;
    int gn4 = (N + 3) / 4;

    // embedding: h0 = relu(x @ W_emb + b_emb)   [N,64]
    gemm_kernel<true, true><<<dim3(gm, 1), 256, 0, stream>>>(x, W_emb, b_emb, bufA, N, 128, 64);

    // GAT layer 0 (4 heads, concat, relu)
    gemm_kernel<false, false><<<dim3(gm, 4), 256, 0, stream>>>(bufA, W0, nullptr, bufB, N, 64, 256);
    alphas_kernel<4><<<gn4, 256, 0, stream>>>(bufB, as0, ad0, aS, aD, N);
    aggregate_kernel<4, true><<<gn4, 256, 0, stream>>>(bufB, aS, aD, row_ptr, csr, b0, bufA, N);

    // GAT layer 1
    gemm_kernel<false, false><<<dim3(gm, 4), 256, 0, stream>>>(bufA, W1, nullptr, bufB, N, 256, 256);
    alphas_kernel<4><<<gn4, 256, 0, stream>>>(bufB, as1, ad1, aS, aD, N);
    aggregate_kernel<4, true><<<gn4, 256, 0, stream>>>(bufB, aS, aD, row_ptr, csr, b1, bufA, N);

    // GAT layer 2 (1 head, mean over 1 head == identity, no relu)
    gemm_kernel<false, false><<<dim3(gm, 1), 256, 0, stream>>>(bufA, W2, nullptr, bufB, N, 256, 64);
    alphas_kernel<1><<<gn4, 256, 0, stream>>>(bufB, as2, ad2, aS, aD, N);
    aggregate_kernel<1, false><<<gn4, 256, 0, stream>>>(bufB, aS, aD, row_ptr, csr, b2, bufA, N);

    // head MLP -> out [N,1] fp32
    mlp_head_kernel<<<(N + 255) / 256, 256, 0, stream>>>(bufA, Wo1, bo1, Wo2, bo2, (float*)d_out, N);
}

// Round 4
// 832.839 us; speedup vs baseline: 1.1708x; 1.1708x over previous
//
#include <hip/hip_runtime.h>

__device__ __forceinline__ float leaky(float v) { return v >= 0.f ? v : 0.2f * v; }

// ---------------- CSR build ----------------
__global__ void hist_kernel(const int* __restrict__ dst, int E, int* __restrict__ cnt) {
    int e = blockIdx.x * blockDim.x + threadIdx.x;
    if (e < E) atomicAdd(&cnt[dst[e]], 1);
}

__global__ __launch_bounds__(1024) void scan_kernel(const int* __restrict__ cnt,
                                                    int* __restrict__ row_ptr,
                                                    int* __restrict__ cursor, int N) {
    __shared__ int part[1024];
    int tid = threadIdx.x;
    int per = (N + 1023) >> 10;
    int s0 = tid * per, s1 = min(s0 + per, N);
    int s = 0;
    for (int i = s0; i < s1; i++) s += cnt[i] + 1;  // +1 = self loop
    part[tid] = s;
    __syncthreads();
    for (int off = 1; off < 1024; off <<= 1) {
        int v = (tid >= off) ? part[tid - off] : 0;
        __syncthreads();
        part[tid] += v;
        __syncthreads();
    }
    int base = (tid == 0) ? 0 : part[tid - 1];
    for (int i = s0; i < s1; i++) {
        row_ptr[i] = base; cursor[i] = base;
        base += cnt[i] + 1;
    }
    if (tid == 0) row_ptr[N] = part[1023];
}

__global__ void scatter_kernel(const int* __restrict__ src, const int* __restrict__ dst,
                               int E, int N, int* __restrict__ cursor, int* __restrict__ csr_src) {
    int e = blockIdx.x * blockDim.x + threadIdx.x;
    if (e >= E + N) return;
    int s, d;
    if (e < E) { s = src[e]; d = dst[e]; }
    else       { s = e - E;  d = s; }
    int pos = atomicAdd(&cursor[d], 1);
    csr_src[pos] = s;
}

// ---------------- GEMM 128x128, BK=16, 8x8 microtile (Nn multiple of 128) ----------------
template <bool RELU, bool BIAS>
__global__ __launch_bounds__(256) void gemm128_kernel(const float* __restrict__ A,
                                                      const float* __restrict__ B,
                                                      const float* __restrict__ bias,
                                                      float* __restrict__ C,
                                                      int M, int K, int Nn) {
    __shared__ float As[16][132];   // [k][m] transposed, +4 pad
    __shared__ float Bs[16][132];   // [k][n]
    int tid = threadIdx.x;
    int wv = tid >> 6, lane = tid & 63;
    int ty = lane >> 3, tx = lane & 7;
    int row0 = blockIdx.x * 128, col0 = blockIdx.y * 128;
    int mrow = (wv >> 1) * 64 + ty * 8;
    int ncol = (wv & 1) * 64 + tx * 8;
    float acc[8][8] = {};

    for (int kt = 0; kt < K; kt += 16) {
#pragma unroll
        for (int h = 0; h < 2; h++) {
            int e = tid + h * 256;
            int arow = e >> 2, k4 = (e & 3) * 4;
            float4 av = make_float4(0.f, 0.f, 0.f, 0.f);
            if (row0 + arow < M)
                av = *(const float4*)(A + (size_t)(row0 + arow) * K + kt + k4);
            As[k4 + 0][arow] = av.x;
            As[k4 + 1][arow] = av.y;
            As[k4 + 2][arow] = av.z;
            As[k4 + 3][arow] = av.w;
            int krow = e >> 5, c4 = (e & 31) * 4;
            float4 bv = *(const float4*)(B + (size_t)(kt + krow) * Nn + col0 + c4);
            *(float4*)&Bs[krow][c4] = bv;
        }
        __syncthreads();
#pragma unroll
        for (int k = 0; k < 16; k++) {
            float4 a0 = *(const float4*)&As[k][mrow];
            float4 a1 = *(const float4*)&As[k][mrow + 4];
            float4 b0 = *(const float4*)&Bs[k][ncol];
            float4 b1 = *(const float4*)&Bs[k][ncol + 4];
            float av[8] = {a0.x, a0.y, a0.z, a0.w, a1.x, a1.y, a1.z, a1.w};
            float bw[8] = {b0.x, b0.y, b0.z, b0.w, b1.x, b1.y, b1.z, b1.w};
#pragma unroll
            for (int i = 0; i < 8; i++)
#pragma unroll
                for (int j = 0; j < 8; j++) acc[i][j] += av[i] * bw[j];
        }
        __syncthreads();
    }

    float bv[8];
#pragma unroll
    for (int j = 0; j < 8; j++) bv[j] = BIAS ? bias[col0 + ncol + j] : 0.f;
#pragma unroll
    for (int i = 0; i < 8; i++) {
        int r = row0 + mrow + i;
        if (r < M) {
            float4 o0, o1;
            float v;
            v = acc[i][0] + bv[0]; o0.x = RELU ? fmaxf(v, 0.f) : v;
            v = acc[i][1] + bv[1]; o0.y = RELU ? fmaxf(v, 0.f) : v;
            v = acc[i][2] + bv[2]; o0.z = RELU ? fmaxf(v, 0.f) : v;
            v = acc[i][3] + bv[3]; o0.w = RELU ? fmaxf(v, 0.f) : v;
            v = acc[i][4] + bv[4]; o1.x = RELU ? fmaxf(v, 0.f) : v;
            v = acc[i][5] + bv[5]; o1.y = RELU ? fmaxf(v, 0.f) : v;
            v = acc[i][6] + bv[6]; o1.z = RELU ? fmaxf(v, 0.f) : v;
            v = acc[i][7] + bv[7]; o1.w = RELU ? fmaxf(v, 0.f) : v;
            size_t o = (size_t)r * Nn + col0 + ncol;
            *(float4*)(C + o) = o0;
            *(float4*)(C + o + 4) = o1;
        }
    }
}

// ---------------- GEMM 64x64 (for Nn==64) ----------------
template <bool RELU, bool BIAS>
__global__ __launch_bounds__(256) void gemm_kernel(const float* __restrict__ A,
                                                   const float* __restrict__ B,
                                                   const float* __restrict__ bias,
                                                   float* __restrict__ C,
                                                   int M, int K, int Nn) {
    __shared__ float As[64][65];
    __shared__ float Bs[64][68];
    int tid = threadIdx.x;
    int tx = tid & 15, ty = tid >> 4;
    int row0 = blockIdx.x * 64, col0 = blockIdx.y * 64;
    float acc[4][4] = {};

    for (int kt = 0; kt < K; kt += 64) {
        {
            int r = tid >> 2;
            int kc = (tid & 3) * 16;
            int grow = row0 + r;
            if (grow < M) {
                size_t base = (size_t)grow * K + kt + kc;
#pragma unroll
                for (int i = 0; i < 16; i += 4) {
                    float4 v = *(const float4*)(A + base + i);
                    As[r][kc + i + 0] = v.x; As[r][kc + i + 1] = v.y;
                    As[r][kc + i + 2] = v.z; As[r][kc + i + 3] = v.w;
                }
            } else {
#pragma unroll
                for (int i = 0; i < 16; i++) As[r][kc + i] = 0.f;
            }
        }
        {
            int kr = tid >> 2;
            int nc = (tid & 3) * 16;
            size_t base = (size_t)(kt + kr) * Nn + col0 + nc;
#pragma unroll
            for (int i = 0; i < 16; i += 4) {
                float4 v = *(const float4*)(B + base + i);
                Bs[kr][nc + i + 0] = v.x; Bs[kr][nc + i + 1] = v.y;
                Bs[kr][nc + i + 2] = v.z; Bs[kr][nc + i + 3] = v.w;
            }
        }
        __syncthreads();
#pragma unroll
        for (int k = 0; k < 64; k++) {
            float b0v = Bs[k][tx * 4 + 0];
            float b1v = Bs[k][tx * 4 + 1];
            float b2v = Bs[k][tx * 4 + 2];
            float b3v = Bs[k][tx * 4 + 3];
#pragma unroll
            for (int i = 0; i < 4; i++) {
                float av = As[ty * 4 + i][k];
                acc[i][0] += av * b0v;
                acc[i][1] += av * b1v;
                acc[i][2] += av * b2v;
                acc[i][3] += av * b3v;
            }
        }
        __syncthreads();
    }

    float bv0 = 0.f, bv1 = 0.f, bv2 = 0.f, bv3 = 0.f;
    if (BIAS) {
        bv0 = bias[col0 + tx * 4 + 0];
        bv1 = bias[col0 + tx * 4 + 1];
        bv2 = bias[col0 + tx * 4 + 2];
        bv3 = bias[col0 + tx * 4 + 3];
    }
#pragma unroll
    for (int i = 0; i < 4; i++) {
        int r = row0 + ty * 4 + i;
        if (r < M) {
            float v0 = acc[i][0] + bv0;
            float v1 = acc[i][1] + bv1;
            float v2 = acc[i][2] + bv2;
            float v3 = acc[i][3] + bv3;
            if (RELU) {
                v0 = fmaxf(v0, 0.f); v1 = fmaxf(v1, 0.f);
                v2 = fmaxf(v2, 0.f); v3 = fmaxf(v3, 0.f);
            }
            size_t o = (size_t)r * Nn + col0 + tx * 4;
            float4 ov = make_float4(v0, v1, v2, v3);
            *(float4*)(C + o) = ov;
        }
    }
}

// ---------------- alpha_s/alpha_d per node ----------------
template <int H>
__global__ __launch_bounds__(256) void alphas_kernel(const float* __restrict__ h,
                                                     const float* __restrict__ a_src,
                                                     const float* __restrict__ a_dst,
                                                     float* __restrict__ alpha_s,
                                                     float* __restrict__ alpha_d, int N) {
    int lane = threadIdx.x & 63;
    int node = blockIdx.x * (blockDim.x >> 6) + (threadIdx.x >> 6);
    if (node >= N) return;
    if (H == 4) {
        int head = lane >> 4;
        int c4 = (lane & 15) * 4;
        const float* hp = h + (size_t)node * 256 + head * 64 + c4;
        float s = 0.f, d = 0.f;
#pragma unroll
        for (int j = 0; j < 4; j++) {
            float hv = hp[j];
            s += hv * a_src[head * 64 + c4 + j];
            d += hv * a_dst[head * 64 + c4 + j];
        }
#pragma unroll
        for (int off = 1; off < 16; off <<= 1) {
            s += __shfl_xor(s, off);
            d += __shfl_xor(d, off);
        }
        if ((lane & 15) == 0) {
            alpha_s[node * 4 + head] = s;
            alpha_d[node * 4 + head] = d;
        }
    } else {
        float hv = h[(size_t)node * 64 + lane];
        float s = hv * a_src[lane];
        float d = hv * a_dst[lane];
#pragma unroll
        for (int off = 1; off < 64; off <<= 1) {
            s += __shfl_xor(s, off);
            d += __shfl_xor(d, off);
        }
        if (lane == 0) { alpha_s[node] = s; alpha_d[node] = d; }
    }
}

// ---------------- aggregation, H=4: lane-parallel softmax, LDS-staged weights ----------------
template <bool RELU>
__global__ __launch_bounds__(256) void aggregate4_kernel(const float* __restrict__ hsrc,
                                                         const float* __restrict__ alpha_s,
                                                         const float* __restrict__ alpha_d,
                                                         const int* __restrict__ row_ptr,
                                                         const int* __restrict__ csr_src,
                                                         const float* __restrict__ bias,
                                                         float* __restrict__ out, int N) {
    __shared__ float wlds[4][64][4];
    __shared__ int   slds[4][64];
    int wv = threadIdx.x >> 6, lane = threadIdx.x & 63;
    int node = blockIdx.x * 4 + wv;
    if (node >= N) return;
    int rs = row_ptr[node], re = row_ptr[node + 1];
    int head = lane >> 4, c4 = (lane & 15) * 4;
    float4 ad4 = *(const float4*)(alpha_d + (size_t)node * 4);

    // pass A: lane-parallel max per head
    float m0 = -1e30f, m1 = -1e30f, m2 = -1e30f, m3 = -1e30f;
    for (int base = rs; base < re; base += 64) {
        int i = base + lane;
        if (i < re) {
            int s = csr_src[i];
            float4 as = *(const float4*)(alpha_s + (size_t)s * 4);
            m0 = fmaxf(m0, leaky(as.x + ad4.x));
            m1 = fmaxf(m1, leaky(as.y + ad4.y));
            m2 = fmaxf(m2, leaky(as.z + ad4.z));
            m3 = fmaxf(m3, leaky(as.w + ad4.w));
        }
    }
#pragma unroll
    for (int off = 32; off >= 1; off >>= 1) {
        m0 = fmaxf(m0, __shfl_xor(m0, off));
        m1 = fmaxf(m1, __shfl_xor(m1, off));
        m2 = fmaxf(m2, __shfl_xor(m2, off));
        m3 = fmaxf(m3, __shfl_xor(m3, off));
    }

    // pass B: lane-parallel weights -> LDS; serial channel accumulate from LDS
    float den0 = 0.f, den1 = 0.f, den2 = 0.f, den3 = 0.f;
    float a0 = 0.f, a1 = 0.f, a2 = 0.f, a3 = 0.f;
    float* wp = &wlds[wv][0][0];
    int*   sp = &slds[wv][0];
    for (int base = rs; base < re; base += 64) {
        int i = base + lane;
        float w0 = 0.f, w1 = 0.f, w2 = 0.f, w3 = 0.f;
        int s = 0;
        if (i < re) {
            s = csr_src[i];
            float4 as = *(const float4*)(alpha_s + (size_t)s * 4);
            w0 = __expf(leaky(as.x + ad4.x) - m0);
            w1 = __expf(leaky(as.y + ad4.y) - m1);
            w2 = __expf(leaky(as.z + ad4.z) - m2);
            w3 = __expf(leaky(as.w + ad4.w) - m3);
        }
        den0 += w0; den1 += w1; den2 += w2; den3 += w3;
        sp[lane] = s;
        *(float4*)(wp + lane * 4) = make_float4(w0, w1, w2, w3);
        int cnt = min(64, re - base);
#pragma unroll 4
        for (int j = 0; j < cnt; j++) {
            int s2 = sp[j];
            float w = wp[j * 4 + head];
            const float* hp = hsrc + (size_t)s2 * 256 + (head << 6) + c4;
            a0 += w * hp[0]; a1 += w * hp[1]; a2 += w * hp[2]; a3 += w * hp[3];
        }
    }
#pragma unroll
    for (int off = 32; off >= 1; off >>= 1) {
        den0 += __shfl_xor(den0, off);
        den1 += __shfl_xor(den1, off);
        den2 += __shfl_xor(den2, off);
        den3 += __shfl_xor(den3, off);
    }
    float den = (head & 2) ? ((head & 1) ? den3 : den2) : ((head & 1) ? den1 : den0);
    float inv = 1.f / (den + 1e-16f);
    int cbase = (head << 6) + c4;
    float v0 = a0 * inv + bias[cbase + 0];
    float v1 = a1 * inv + bias[cbase + 1];
    float v2 = a2 * inv + bias[cbase + 2];
    float v3 = a3 * inv + bias[cbase + 3];
    if (RELU) {
        v0 = fmaxf(v0, 0.f); v1 = fmaxf(v1, 0.f);
        v2 = fmaxf(v2, 0.f); v3 = fmaxf(v3, 0.f);
    }
    *(float4*)(out + (size_t)node * 256 + cbase) = make_float4(v0, v1, v2, v3);
}

// ---------------- aggregation, H=1 ----------------
template <bool RELU>
__global__ __launch_bounds__(256) void aggregate1_kernel(const float* __restrict__ hsrc,
                                                         const float* __restrict__ alpha_s,
                                                         const float* __restrict__ alpha_d,
                                                         const int* __restrict__ row_ptr,
                                                         const int* __restrict__ csr_src,
                                                         const float* __restrict__ bias,
                                                         float* __restrict__ out, int N) {
    __shared__ float wlds[4][64];
    __shared__ int   slds[4][64];
    int wv = threadIdx.x >> 6, lane = threadIdx.x & 63;
    int node = blockIdx.x * 4 + wv;
    if (node >= N) return;
    int rs = row_ptr[node], re = row_ptr[node + 1];
    float ad = alpha_d[node];

    float m = -1e30f;
    for (int base = rs; base < re; base += 64) {
        int i = base + lane;
        if (i < re) {
            int s = csr_src[i];
            m = fmaxf(m, leaky(alpha_s[s] + ad));
        }
    }
#pragma unroll
    for (int off = 32; off >= 1; off >>= 1) m = fmaxf(m, __shfl_xor(m, off));

    float den = 0.f, acc = 0.f;
    float* wp = &wlds[wv][0];
    int*   sp = &slds[wv][0];
    for (int base = rs; base < re; base += 64) {
        int i = base + lane;
        float w = 0.f;
        int s = 0;
        if (i < re) {
            s = csr_src[i];
            w = __expf(leaky(alpha_s[s] + ad) - m);
        }
        den += w;
        sp[lane] = s;
        wp[lane] = w;
        int cnt = min(64, re - base);
#pragma unroll 4
        for (int j = 0; j < cnt; j++) {
            int s2 = sp[j];
            acc += wp[j] * hsrc[(size_t)s2 * 64 + lane];
        }
    }
#pragma unroll
    for (int off = 32; off >= 1; off >>= 1) den += __shfl_xor(den, off);
    float v = acc / (den + 1e-16f) + bias[lane];
    if (RELU) v = fmaxf(v, 0.f);
    out[(size_t)node * 64 + lane] = v;
}

// ---------------- head MLP ----------------
__global__ __launch_bounds__(256) void mlp_head_kernel(const float* __restrict__ hin,
                                                       const float* __restrict__ Wo1,
                                                       const float* __restrict__ bo1,
                                                       const float* __restrict__ Wo2,
                                                       const float* __restrict__ bo2,
                                                       float* __restrict__ out, int N) {
    __shared__ float w1[64 * 32];
    __shared__ float w2[32];
    __shared__ float b1s[32];
    int tid = threadIdx.x;
#pragma unroll
    for (int i = 0; i < 8; i++) w1[tid + i * 256] = Wo1[tid + i * 256];
    if (tid < 32) { w2[tid] = Wo2[tid]; b1s[tid] = bo1[tid]; }
    __syncthreads();
    int n = blockIdx.x * blockDim.x + tid;
    if (n >= N) return;
    float hrow[64];
    const float* pr = hin + (size_t)n * 64;
#pragma unroll
    for (int i = 0; i < 64; i++) hrow[i] = pr[i];
    float sum = 0.f;
    for (int j = 0; j < 32; j++) {
        float a = b1s[j];
#pragma unroll
        for (int k = 0; k < 64; k++) a += hrow[k] * w1[k * 32 + j];
        a = fmaxf(a, 0.f);
        sum += a * w2[j];
    }
    out[n] = sum + bo2[0];
}

// ---------------- launch ----------------
extern "C" void kernel_launch(void* const* d_in, const int* in_sizes, int n_in,
                              void* d_out, int out_size, void* d_ws, size_t ws_size,
                              hipStream_t stream) {
    const float* x     = (const float*)d_in[0];
    const float* W_emb = (const float*)d_in[1];
    const float* b_emb = (const float*)d_in[2];
    const float* W0    = (const float*)d_in[3];
    const float* as0   = (const float*)d_in[4];
    const float* ad0   = (const float*)d_in[5];
    const float* b0    = (const float*)d_in[6];
    const float* W1    = (const float*)d_in[7];
    const float* as1   = (const float*)d_in[8];
    const float* ad1   = (const float*)d_in[9];
    const float* b1    = (const float*)d_in[10];
    const float* W2    = (const float*)d_in[11];
    const float* as2   = (const float*)d_in[12];
    const float* ad2   = (const float*)d_in[13];
    const float* b2    = (const float*)d_in[14];
    const float* Wo1   = (const float*)d_in[15];
    const float* bo1   = (const float*)d_in[16];
    const float* Wo2   = (const float*)d_in[17];
    const float* bo2   = (const float*)d_in[18];
    const int* eidx    = (const int*)d_in[19];

    const int N = in_sizes[0] / 128;
    const int E = in_sizes[19] / 2;
    const int* esrc = eidx;
    const int* edst = eidx + E;

    char* w = (char*)d_ws;
    auto alloc = [&](size_t bytes) {
        char* p = w;
        w += (bytes + 255) & ~(size_t)255;
        return (void*)p;
    };
    float* bufA    = (float*)alloc((size_t)N * 256 * 4);
    float* bufB    = (float*)alloc((size_t)N * 256 * 4);
    float* aS      = (float*)alloc((size_t)N * 4 * 4);
    float* aD      = (float*)alloc((size_t)N * 4 * 4);
    int*   row_ptr = (int*)alloc((size_t)(N + 1) * 4);
    int*   cursor  = (int*)alloc((size_t)N * 4);
    int*   cnt     = (int*)alloc((size_t)N * 4);
    int*   csr     = (int*)alloc((size_t)(E + N) * 4);

    hipMemsetAsync(cnt, 0, (size_t)N * 4, stream);
    hist_kernel<<<(E + 255) / 256, 256, 0, stream>>>(edst, E, cnt);
    scan_kernel<<<1, 1024, 0, stream>>>(cnt, row_ptr, cursor, N);
    scatter_kernel<<<(E + N + 255) / 256, 256, 0, stream>>>(esrc, edst, E, N, cursor, csr);

    int gm64  = (N + 63) / 64;
    int gm128 = (N + 127) / 128;
    int gn4   = (N + 3) / 4;

    // embedding: h0 = relu(x @ W_emb + b_emb)   [N,64]
    gemm_kernel<true, true><<<dim3(gm64, 1), 256, 0, stream>>>(x, W_emb, b_emb, bufA, N, 128, 64);

    // GAT layer 0 (4 heads, concat, relu)
    gemm128_kernel<false, false><<<dim3(gm128, 2), 256, 0, stream>>>(bufA, W0, nullptr, bufB, N, 64, 256);
    alphas_kernel<4><<<gn4, 256, 0, stream>>>(bufB, as0, ad0, aS, aD, N);
    aggregate4_kernel<true><<<gn4, 256, 0, stream>>>(bufB, aS, aD, row_ptr, csr, b0, bufA, N);

    // GAT layer 1
    gemm128_kernel<false, false><<<dim3(gm128, 2), 256, 0, stream>>>(bufA, W1, nullptr, bufB, N, 256, 256);
    alphas_kernel<4><<<gn4, 256, 0, stream>>>(bufB, as1, ad1, aS, aD, N);
    aggregate4_kernel<true><<<gn4, 256, 0, stream>>>(bufB, aS, aD, row_ptr, csr, b1, bufA, N);

    // GAT layer 2 (1 head, no relu)
    gemm_kernel<false, false><<<dim3(gm64, 1), 256, 0, stream>>>(bufA, W2, nullptr, bufB, N, 256, 64);
    alphas_kernel<1><<<gn4, 256, 0, stream>>>(bufB, as2, ad2, aS, aD, N);
    aggregate1_kernel<false><<<gn4, 256, 0, stream>>>(bufB, aS, aD, row_ptr, csr, b2, bufA, N);

    // head MLP -> out [N,1] fp32
    mlp_head_kernel<<<(N + 255) / 256, 256, 0, stream>>>(bufA, Wo1, bo1, Wo2, bo2, (float*)d_out, N);
}

// Round 5
// 756.570 us; speedup vs baseline: 1.2888x; 1.1008x over previous
//
#include <hip/hip_runtime.h>

typedef _Float16 half8 __attribute__((ext_vector_type(8)));
typedef float floatx4 __attribute__((ext_vector_type(4)));

__device__ __forceinline__ float leaky(float v) { return v >= 0.f ? v : 0.2f * v; }

// ---------------- CSR build ----------------
__global__ void hist_kernel(const int* __restrict__ dst, int E, int* __restrict__ cnt) {
    int e = blockIdx.x * blockDim.x + threadIdx.x;
    if (e < E) atomicAdd(&cnt[dst[e]], 1);
}

__global__ __launch_bounds__(1024) void scan_kernel(const int* __restrict__ cnt,
                                                    int* __restrict__ row_ptr,
                                                    int* __restrict__ cursor, int N) {
    __shared__ int part[1024];
    int tid = threadIdx.x;
    int per = (N + 1023) >> 10;
    int s0 = tid * per, s1 = min(s0 + per, N);
    int s = 0;
    for (int i = s0; i < s1; i++) s += cnt[i] + 1;  // +1 = self loop
    part[tid] = s;
    __syncthreads();
    for (int off = 1; off < 1024; off <<= 1) {
        int v = (tid >= off) ? part[tid - off] : 0;
        __syncthreads();
        part[tid] += v;
        __syncthreads();
    }
    int base = (tid == 0) ? 0 : part[tid - 1];
    for (int i = s0; i < s1; i++) {
        row_ptr[i] = base; cursor[i] = base;
        base += cnt[i] + 1;
    }
    if (tid == 0) row_ptr[N] = part[1023];
}

__global__ void scatter_kernel(const int* __restrict__ src, const int* __restrict__ dst,
                               int E, int N, int* __restrict__ cursor, int* __restrict__ csr_src) {
    int e = blockIdx.x * blockDim.x + threadIdx.x;
    if (e >= E + N) return;
    int s, d;
    if (e < E) { s = src[e]; d = dst[e]; }
    else       { s = e - E;  d = s; }
    int pos = atomicAdd(&cursor[d], 1);
    csr_src[pos] = s;
}

// ---------------- weight prep: fp32 [K,N] -> f16 hi/lo planes in frag order [K/8][N][8] ----------------
__global__ void prep_weight_kernel(const float* __restrict__ W,
                                   _Float16* __restrict__ Wh, _Float16* __restrict__ Wl,
                                   int K, int N) {
    int idx = blockIdx.x * blockDim.x + threadIdx.x;
    if (idx >= K * N) return;
    int k = idx / N, n = idx % N;
    float v = W[idx];
    _Float16 hi = (_Float16)v;
    _Float16 lo = (_Float16)(v - (float)hi);
    size_t o = ((size_t)(k >> 3) * N + n) * 8 + (k & 7);
    Wh[o] = hi; Wl[o] = lo;
}

// ---------------- MFMA GEMM: C[M,Nn] = A[M,K]*B[K,Nn], split-f16 (3 mfma / tile) ----------------
// BM=128, BN=CT*16, BK=32. Wave wv owns rows [wv*32, wv*32+32), all BN cols.
// A frag: A[m=lane&15][k=quad*8+j]; B frag: B[k=quad*8+j][n=lane&15];
// C/D frag: col=lane&15, row=quad*4+reg.
template <int CT, bool RELU, bool BIAS>
__global__ __launch_bounds__(256) void gemm_mfma_kernel(const float* __restrict__ A,
                                                        const _Float16* __restrict__ Bh,
                                                        const _Float16* __restrict__ Bl,
                                                        const float* __restrict__ bias,
                                                        float* __restrict__ C,
                                                        int M, int K, int Nn) {
    __shared__ __align__(16) _Float16 AhL[4][128][8];
    __shared__ __align__(16) _Float16 AlL[4][128][8];
    int tid = threadIdx.x;
    int wv = tid >> 6, lane = tid & 63;
    int m16 = lane & 15, quad = lane >> 4;
    int row0 = blockIdx.x * 128;
    int col0 = blockIdx.y * (CT * 16);
    int sr = tid & 127;          // staging row
    int skg = tid >> 7;          // staging k-group (0/1)

    floatx4 acc[2][CT];
#pragma unroll
    for (int t = 0; t < 2; t++)
#pragma unroll
        for (int c = 0; c < CT; c++)
#pragma unroll
            for (int i = 0; i < 4; i++) acc[t][c][i] = 0.f;

    for (int kt = 0; kt < K; kt += 32) {
        // ---- stage A tile (128 x 32) as f16 hi/lo planes [plane][row][8] ----
#pragma unroll
        for (int h = 0; h < 2; h++) {
            int plane = skg + 2 * h;
            int gr = row0 + sr;
            float vs[8] = {0.f, 0.f, 0.f, 0.f, 0.f, 0.f, 0.f, 0.f};
            if (gr < M) {
                const float4* pA = (const float4*)(A + (size_t)gr * K + kt + plane * 8);
                float4 v0 = pA[0], v1 = pA[1];
                vs[0] = v0.x; vs[1] = v0.y; vs[2] = v0.z; vs[3] = v0.w;
                vs[4] = v1.x; vs[5] = v1.y; vs[6] = v1.z; vs[7] = v1.w;
            }
            half8 hh, hl;
#pragma unroll
            for (int j = 0; j < 8; j++) {
                _Float16 hi = (_Float16)vs[j];
                hh[j] = hi;
                hl[j] = (_Float16)(vs[j] - (float)hi);
            }
            *reinterpret_cast<half8*>(&AhL[plane][sr][0]) = hh;
            *reinterpret_cast<half8*>(&AlL[plane][sr][0]) = hl;
        }
        __syncthreads();

        // ---- A fragments (2 row-tiles) ----
        half8 ah[2], al[2];
#pragma unroll
        for (int t = 0; t < 2; t++) {
            int r = wv * 32 + t * 16 + m16;
            ah[t] = *reinterpret_cast<const half8*>(&AhL[quad][r][0]);
            al[t] = *reinterpret_cast<const half8*>(&AlL[quad][r][0]);
        }

        // ---- per col-tile: load B frags from pre-swizzled global (L2-hot), 3 mfma each ----
        size_t kqbase = ((size_t)(kt >> 3) + quad) * Nn;
#pragma unroll
        for (int c = 0; c < CT; c++) {
            size_t bo = (kqbase + col0 + c * 16 + m16) * 8;
            half8 bh = *reinterpret_cast<const half8*>(Bh + bo);
            half8 bl = *reinterpret_cast<const half8*>(Bl + bo);
#pragma unroll
            for (int t = 0; t < 2; t++) {
                acc[t][c] = __builtin_amdgcn_mfma_f32_16x16x32_f16(ah[t], bh, acc[t][c], 0, 0, 0);
                acc[t][c] = __builtin_amdgcn_mfma_f32_16x16x32_f16(ah[t], bl, acc[t][c], 0, 0, 0);
                acc[t][c] = __builtin_amdgcn_mfma_f32_16x16x32_f16(al[t], bh, acc[t][c], 0, 0, 0);
            }
        }
        __syncthreads();
    }

    // ---- epilogue ----
#pragma unroll
    for (int t = 0; t < 2; t++) {
#pragma unroll
        for (int c = 0; c < CT; c++) {
            int col = col0 + c * 16 + m16;
            float bv = BIAS ? bias[col] : 0.f;
#pragma unroll
            for (int i = 0; i < 4; i++) {
                int r = row0 + wv * 32 + t * 16 + quad * 4 + i;
                if (r < M) {
                    float v = acc[t][c][i] + bv;
                    if (RELU) v = fmaxf(v, 0.f);
                    C[(size_t)r * Nn + col] = v;
                }
            }
        }
    }
}

// ---------------- alpha_s/alpha_d per node ----------------
template <int H>
__global__ __launch_bounds__(256) void alphas_kernel(const float* __restrict__ h,
                                                     const float* __restrict__ a_src,
                                                     const float* __restrict__ a_dst,
                                                     float* __restrict__ alpha_s,
                                                     float* __restrict__ alpha_d, int N) {
    int lane = threadIdx.x & 63;
    int node = blockIdx.x * (blockDim.x >> 6) + (threadIdx.x >> 6);
    if (node >= N) return;
    if (H == 4) {
        int head = lane >> 4;
        int c4 = (lane & 15) * 4;
        const float* hp = h + (size_t)node * 256 + head * 64 + c4;
        float s = 0.f, d = 0.f;
#pragma unroll
        for (int j = 0; j < 4; j++) {
            float hv = hp[j];
            s += hv * a_src[head * 64 + c4 + j];
            d += hv * a_dst[head * 64 + c4 + j];
        }
#pragma unroll
        for (int off = 1; off < 16; off <<= 1) {
            s += __shfl_xor(s, off);
            d += __shfl_xor(d, off);
        }
        if ((lane & 15) == 0) {
            alpha_s[node * 4 + head] = s;
            alpha_d[node * 4 + head] = d;
        }
    } else {
        float hv = h[(size_t)node * 64 + lane];
        float s = hv * a_src[lane];
        float d = hv * a_dst[lane];
#pragma unroll
        for (int off = 1; off < 64; off <<= 1) {
            s += __shfl_xor(s, off);
            d += __shfl_xor(d, off);
        }
        if (lane == 0) { alpha_s[node] = s; alpha_d[node] = d; }
    }
}

// ---------------- aggregation, H=4 ----------------
template <bool RELU>
__global__ __launch_bounds__(256) void aggregate4_kernel(const float* __restrict__ hsrc,
                                                         const float* __restrict__ alpha_s,
                                                         const float* __restrict__ alpha_d,
                                                         const int* __restrict__ row_ptr,
                                                         const int* __restrict__ csr_src,
                                                         const float* __restrict__ bias,
                                                         float* __restrict__ out, int N) {
    __shared__ float wlds[4][64][4];
    __shared__ int   slds[4][64];
    int wv = threadIdx.x >> 6, lane = threadIdx.x & 63;
    int node = blockIdx.x * 4 + wv;
    if (node >= N) return;
    int rs = row_ptr[node], re = row_ptr[node + 1];
    int head = lane >> 4, c4 = (lane & 15) * 4;
    float4 ad4 = *(const float4*)(alpha_d + (size_t)node * 4);

    float m0 = -1e30f, m1 = -1e30f, m2 = -1e30f, m3 = -1e30f;
    for (int base = rs; base < re; base += 64) {
        int i = base + lane;
        if (i < re) {
            int s = csr_src[i];
            float4 as = *(const float4*)(alpha_s + (size_t)s * 4);
            m0 = fmaxf(m0, leaky(as.x + ad4.x));
            m1 = fmaxf(m1, leaky(as.y + ad4.y));
            m2 = fmaxf(m2, leaky(as.z + ad4.z));
            m3 = fmaxf(m3, leaky(as.w + ad4.w));
        }
    }
#pragma unroll
    for (int off = 32; off >= 1; off >>= 1) {
        m0 = fmaxf(m0, __shfl_xor(m0, off));
        m1 = fmaxf(m1, __shfl_xor(m1, off));
        m2 = fmaxf(m2, __shfl_xor(m2, off));
        m3 = fmaxf(m3, __shfl_xor(m3, off));
    }

    float den0 = 0.f, den1 = 0.f, den2 = 0.f, den3 = 0.f;
    float a0 = 0.f, a1 = 0.f, a2 = 0.f, a3 = 0.f;
    float* wp = &wlds[wv][0][0];
    int*   sp = &slds[wv][0];
    for (int base = rs; base < re; base += 64) {
        int i = base + lane;
        float w0 = 0.f, w1 = 0.f, w2 = 0.f, w3 = 0.f;
        int s = 0;
        if (i < re) {
            s = csr_src[i];
            float4 as = *(const float4*)(alpha_s + (size_t)s * 4);
            w0 = __expf(leaky(as.x + ad4.x) - m0);
            w1 = __expf(leaky(as.y + ad4.y) - m1);
            w2 = __expf(leaky(as.z + ad4.z) - m2);
            w3 = __expf(leaky(as.w + ad4.w) - m3);
        }
        den0 += w0; den1 += w1; den2 += w2; den3 += w3;
        sp[lane] = s;
        *(float4*)(wp + lane * 4) = make_float4(w0, w1, w2, w3);
        int cnt = min(64, re - base);
#pragma unroll 4
        for (int j = 0; j < cnt; j++) {
            int s2 = sp[j];
            float w = wp[j * 4 + head];
            const float* hp = hsrc + (size_t)s2 * 256 + (head << 6) + c4;
            a0 += w * hp[0]; a1 += w * hp[1]; a2 += w * hp[2]; a3 += w * hp[3];
        }
    }
#pragma unroll
    for (int off = 32; off >= 1; off >>= 1) {
        den0 += __shfl_xor(den0, off);
        den1 += __shfl_xor(den1, off);
        den2 += __shfl_xor(den2, off);
        den3 += __shfl_xor(den3, off);
    }
    float den = (head & 2) ? ((head & 1) ? den3 : den2) : ((head & 1) ? den1 : den0);
    float inv = 1.f / (den + 1e-16f);
    int cbase = (head << 6) + c4;
    float v0 = a0 * inv + bias[cbase + 0];
    float v1 = a1 * inv + bias[cbase + 1];
    float v2 = a2 * inv + bias[cbase + 2];
    float v3 = a3 * inv + bias[cbase + 3];
    if (RELU) {
        v0 = fmaxf(v0, 0.f); v1 = fmaxf(v1, 0.f);
        v2 = fmaxf(v2, 0.f); v3 = fmaxf(v3, 0.f);
    }
    *(float4*)(out + (size_t)node * 256 + cbase) = make_float4(v0, v1, v2, v3);
}

// ---------------- aggregation, H=1 ----------------
template <bool RELU>
__global__ __launch_bounds__(256) void aggregate1_kernel(const float* __restrict__ hsrc,
                                                         const float* __restrict__ alpha_s,
                                                         const float* __restrict__ alpha_d,
                                                         const int* __restrict__ row_ptr,
                                                         const int* __restrict__ csr_src,
                                                         const float* __restrict__ bias,
                                                         float* __restrict__ out, int N) {
    __shared__ float wlds[4][64];
    __shared__ int   slds[4][64];
    int wv = threadIdx.x >> 6, lane = threadIdx.x & 63;
    int node = blockIdx.x * 4 + wv;
    if (node >= N) return;
    int rs = row_ptr[node], re = row_ptr[node + 1];
    float ad = alpha_d[node];

    float m = -1e30f;
    for (int base = rs; base < re; base += 64) {
        int i = base + lane;
        if (i < re) {
            int s = csr_src[i];
            m = fmaxf(m, leaky(alpha_s[s] + ad));
        }
    }
#pragma unroll
    for (int off = 32; off >= 1; off >>= 1) m = fmaxf(m, __shfl_xor(m, off));

    float den = 0.f, acc = 0.f;
    float* wp = &wlds[wv][0];
    int*   sp = &slds[wv][0];
    for (int base = rs; base < re; base += 64) {
        int i = base + lane;
        float w = 0.f;
        int s = 0;
        if (i < re) {
            s = csr_src[i];
            w = __expf(leaky(alpha_s[s] + ad) - m);
        }
        den += w;
        sp[lane] = s;
        wp[lane] = w;
        int cnt = min(64, re - base);
#pragma unroll 4
        for (int j = 0; j < cnt; j++) {
            int s2 = sp[j];
            acc += wp[j] * hsrc[(size_t)s2 * 64 + lane];
        }
    }
#pragma unroll
    for (int off = 32; off >= 1; off >>= 1) den += __shfl_xor(den, off);
    float v = acc / (den + 1e-16f) + bias[lane];
    if (RELU) v = fmaxf(v, 0.f);
    out[(size_t)node * 64 + lane] = v;
}

// ---------------- head MLP ----------------
__global__ __launch_bounds__(256) void mlp_head_kernel(const float* __restrict__ hin,
                                                       const float* __restrict__ Wo1,
                                                       const float* __restrict__ bo1,
                                                       const float* __restrict__ Wo2,
                                                       const float* __restrict__ bo2,
                                                       float* __restrict__ out, int N) {
    __shared__ float w1[64 * 32];
    __shared__ float w2[32];
    __shared__ float b1s[32];
    int tid = threadIdx.x;
#pragma unroll
    for (int i = 0; i < 8; i++) w1[tid + i * 256] = Wo1[tid + i * 256];
    if (tid < 32) { w2[tid] = Wo2[tid]; b1s[tid] = bo1[tid]; }
    __syncthreads();
    int n = blockIdx.x * blockDim.x + tid;
    if (n >= N) return;
    float hrow[64];
    const float* pr = hin + (size_t)n * 64;
#pragma unroll
    for (int i = 0; i < 64; i++) hrow[i] = pr[i];
    float sum = 0.f;
    for (int j = 0; j < 32; j++) {
        float a = b1s[j];
#pragma unroll
        for (int k = 0; k < 64; k++) a += hrow[k] * w1[k * 32 + j];
        a = fmaxf(a, 0.f);
        sum += a * w2[j];
    }
    out[n] = sum + bo2[0];
}

// ---------------- launch ----------------
extern "C" void kernel_launch(void* const* d_in, const int* in_sizes, int n_in,
                              void* d_out, int out_size, void* d_ws, size_t ws_size,
                              hipStream_t stream) {
    const float* x     = (const float*)d_in[0];
    const float* W_emb = (const float*)d_in[1];
    const float* b_emb = (const float*)d_in[2];
    const float* W0    = (const float*)d_in[3];
    const float* as0   = (const float*)d_in[4];
    const float* ad0   = (const float*)d_in[5];
    const float* b0    = (const float*)d_in[6];
    const float* W1    = (const float*)d_in[7];
    const float* as1   = (const float*)d_in[8];
    const float* ad1   = (const float*)d_in[9];
    const float* b1    = (const float*)d_in[10];
    const float* W2    = (const float*)d_in[11];
    const float* as2   = (const float*)d_in[12];
    const float* ad2   = (const float*)d_in[13];
    const float* b2    = (const float*)d_in[14];
    const float* Wo1   = (const float*)d_in[15];
    const float* bo1   = (const float*)d_in[16];
    const float* Wo2   = (const float*)d_in[17];
    const float* bo2   = (const float*)d_in[18];
    const int* eidx    = (const int*)d_in[19];

    const int N = in_sizes[0] / 128;
    const int E = in_sizes[19] / 2;
    const int* esrc = eidx;
    const int* edst = eidx + E;

    char* w = (char*)d_ws;
    auto alloc = [&](size_t bytes) {
        char* p = w;
        w += (bytes + 255) & ~(size_t)255;
        return (void*)p;
    };
    float* bufA    = (float*)alloc((size_t)N * 256 * 4);
    float* bufB    = (float*)alloc((size_t)N * 256 * 4);
    float* aS      = (float*)alloc((size_t)N * 4 * 4);
    float* aD      = (float*)alloc((size_t)N * 4 * 4);
    int*   row_ptr = (int*)alloc((size_t)(N + 1) * 4);
    int*   cursor  = (int*)alloc((size_t)N * 4);
    int*   cnt     = (int*)alloc((size_t)N * 4);
    int*   csr     = (int*)alloc((size_t)(E + N) * 4);
    _Float16* WeH  = (_Float16*)alloc(128 * 64 * 2);
    _Float16* WeL  = (_Float16*)alloc(128 * 64 * 2);
    _Float16* W0H  = (_Float16*)alloc(64 * 256 * 2);
    _Float16* W0L  = (_Float16*)alloc(64 * 256 * 2);
    _Float16* W1H  = (_Float16*)alloc(256 * 256 * 2);
    _Float16* W1L  = (_Float16*)alloc(256 * 256 * 2);
    _Float16* W2H  = (_Float16*)alloc(256 * 64 * 2);
    _Float16* W2L  = (_Float16*)alloc(256 * 64 * 2);

    // CSR build
    hipMemsetAsync(cnt, 0, (size_t)N * 4, stream);
    hist_kernel<<<(E + 255) / 256, 256, 0, stream>>>(edst, E, cnt);
    scan_kernel<<<1, 1024, 0, stream>>>(cnt, row_ptr, cursor, N);
    scatter_kernel<<<(E + N + 255) / 256, 256, 0, stream>>>(esrc, edst, E, N, cursor, csr);

    // weight prep (f16 hi/lo, fragment order)
    prep_weight_kernel<<<(128 * 64 + 255) / 256, 256, 0, stream>>>(W_emb, WeH, WeL, 128, 64);
    prep_weight_kernel<<<(64 * 256 + 255) / 256, 256, 0, stream>>>(W0, W0H, W0L, 64, 256);
    prep_weight_kernel<<<(256 * 256 + 255) / 256, 256, 0, stream>>>(W1, W1H, W1L, 256, 256);
    prep_weight_kernel<<<(256 * 64 + 255) / 256, 256, 0, stream>>>(W2, W2H, W2L, 256, 64);

    int gmB = (N + 127) / 128;
    int gn4 = (N + 3) / 4;

    // embedding: h0 = relu(x @ W_emb + b_emb)   [N,64]
    gemm_mfma_kernel<4, true, true><<<dim3(gmB, 1), 256, 0, stream>>>(x, WeH, WeL, b_emb, bufA, N, 128, 64);

    // GAT layer 0
    gemm_mfma_kernel<8, false, false><<<dim3(gmB, 2), 256, 0, stream>>>(bufA, W0H, W0L, nullptr, bufB, N, 64, 256);
    alphas_kernel<4><<<gn4, 256, 0, stream>>>(bufB, as0, ad0, aS, aD, N);
    aggregate4_kernel<true><<<gn4, 256, 0, stream>>>(bufB, aS, aD, row_ptr, csr, b0, bufA, N);

    // GAT layer 1
    gemm_mfma_kernel<8, false, false><<<dim3(gmB, 2), 256, 0, stream>>>(bufA, W1H, W1L, nullptr, bufB, N, 256, 256);
    alphas_kernel<4><<<gn4, 256, 0, stream>>>(bufB, as1, ad1, aS, aD, N);
    aggregate4_kernel<true><<<gn4, 256, 0, stream>>>(bufB, aS, aD, row_ptr, csr, b1, bufA, N);

    // GAT layer 2 (1 head, no relu)
    gemm_mfma_kernel<4, false, false><<<dim3(gmB, 1), 256, 0, stream>>>(bufA, W2H, W2L, nullptr, bufB, N, 256, 64);
    alphas_kernel<1><<<gn4, 256, 0, stream>>>(bufB, as2, ad2, aS, aD, N);
    aggregate1_kernel<false><<<gn4, 256, 0, stream>>>(bufB, aS, aD, row_ptr, csr, b2, bufA, N);

    // head MLP -> out [N,1] fp32
    mlp_head_kernel<<<(N + 255) / 256, 256, 0, stream>>>(bufA, Wo1, bo1, Wo2, bo2, (float*)d_out, N);
}